// Round 3
// baseline (316.228 us; speedup 1.0000x reference)
//
#include <hip/hip_runtime.h>
#include <hip/hip_bf16.h>

// Problem constants (fixed by the reference):
//   img [8192,1024] f32, txt [8192,1024] f32, both l2-normalized
//   si=st=4, t=16, tts=1, DENOM=2  -> out[bi][bt] = (right+left)/128
//   out [2048,2048] f32
#define N_ROWS 8192
#define DIM    1024
#define BOUT   2048
#define BM 128
#define BN 128
#define BK 64   // 128 B row stride in LDS = full 32-bank span

typedef unsigned short u16;
typedef __attribute__((ext_vector_type(4))) unsigned short u16x4;
typedef __attribute__((ext_vector_type(4))) float f32v4;    // clang ext-vector (nontemporal-ok)
typedef __attribute__((ext_vector_type(8))) short short8;   // 8 bf16 MFMA A/B frag
typedef __attribute__((ext_vector_type(4))) float f32x4;    // MFMA C/D frag

// fp32 -> bf16 round-to-nearest-even
__device__ __forceinline__ u16 f2bf(float f) {
  unsigned u = __float_as_uint(f);
  u += 0x7fffu + ((u >> 16) & 1u);
  return (u16)(u >> 16);
}

__global__ void cast_kernel(const float* __restrict__ a, const float* __restrict__ b,
                            u16* __restrict__ oa, u16* __restrict__ ob) {
  const size_t i = ((size_t)blockIdx.x * 256 + threadIdx.x) * 4;
  f32v4 va = __builtin_nontemporal_load(reinterpret_cast<const f32v4*>(a + i));
  f32v4 vb = __builtin_nontemporal_load(reinterpret_cast<const f32v4*>(b + i));
  u16x4 ua, ub;
  ua[0] = f2bf(va.x); ua[1] = f2bf(va.y); ua[2] = f2bf(va.z); ua[3] = f2bf(va.w);
  ub[0] = f2bf(vb.x); ub[1] = f2bf(vb.y); ub[2] = f2bf(vb.z); ub[3] = f2bf(vb.w);
  __builtin_nontemporal_store(ua, reinterpret_cast<u16x4*>(oa + i));
  __builtin_nontemporal_store(ub, reinterpret_cast<u16x4*>(ob + i));
}

// async 16B global->LDS copy (hardware dest = wave-uniform base + lane*16)
__device__ __forceinline__ void async_cp16(const u16* g, u16* l) {
  __builtin_amdgcn_global_load_lds(
      (const __attribute__((address_space(1))) void*)g,
      (__attribute__((address_space(3))) void*)l, 16, 0, 0);
}

// NT GEMM (dist = A.B^T) with fused smooth-chamfer 4x4-block epilogue.
// 128x128 block tile, 4 waves (2x2), each wave 4x4 tiles of 16x16x32 MFMA,
// BK=64 (2 MFMA k-steps/iter, 32 MFMA per barrier).
// LDS layout: row r has 8 chunks of 8 bf16; chunk c stored at slot c^(r&7)
// -> ds_read_b128 bank-quad = chunk ^ is bijective per 8 rows -> 2-way (free).
__global__ __launch_bounds__(256) void gemm_chamfer(
    const u16* __restrict__ A, const u16* __restrict__ B, float* __restrict__ out) {
  __shared__ __align__(16) u16 lA[BM * BK];   // 16 KiB
  __shared__ __align__(16) u16 lB[BN * BK];   // 16 KiB

  const int tid  = threadIdx.x;
  const int lane = tid & 63;
  const int wave = tid >> 6;
  const int wm = wave & 1;          // wave row (64 rows)
  const int wn = wave >> 1;         // wave col (64 cols)
  const int bm0 = blockIdx.x * BM;
  const int bn0 = blockIdx.y * BN;

  // staging: pass p (0..3), thread t -> LDS row r = p*32 + (t>>3), slot t&7.
  // global chunk loaded = (t&7) ^ (r&7). Dest = p*4096B + t*16B
  //   = wave-uniform(p*4096 + wave*1024) + lane*16  ✓ for global_load_lds.
  const u16* aSrc[4]; const u16* bSrc[4]; u16* dstA[4]; u16* dstB[4];
#pragma unroll
  for (int p = 0; p < 4; ++p) {
    const int r = p * 32 + (tid >> 3);
    const int c = (tid & 7) ^ (r & 7);
    aSrc[p] = A + (size_t)(bm0 + r) * DIM + c * 8;
    bSrc[p] = B + (size_t)(bn0 + r) * DIM + c * 8;
    dstA[p] = &lA[p * 2048 + tid * 8];
    dstB[p] = &lB[p * 2048 + tid * 8];
  }

  f32x4 acc[4][4] = {};

  const int lm = lane & 15;   // A/B row within 16-tile (= C col)
  const int lq = lane >> 4;   // k-quad for A/B frags; row-quad for C
  // reader slots (elem offsets within a row): chunk kk*4+lq at slot ^(lm&7)
  const int slot0 = ((lq)     ^ (lm & 7)) * 8;   // kk = 0
  const int slot1 = ((lq ^ 4) ^ (lm & 7)) * 8;   // kk = 1
  int rowOffA[4], rowOffB[4];
#pragma unroll
  for (int i = 0; i < 4; ++i) {
    rowOffA[i] = (wm * 64 + i * 16 + lm) * BK;
    rowOffB[i] = (wn * 64 + i * 16 + lm) * BK;
  }

  for (int k = 0; k < DIM; k += BK) {
#pragma unroll
    for (int p = 0; p < 4; ++p) {
      async_cp16(aSrc[p] + k, dstA[p]);
      async_cp16(bSrc[p] + k, dstB[p]);
    }
    __syncthreads();

    short8 af[4], bfv[4];
#pragma unroll
    for (int mt = 0; mt < 4; ++mt) {
      af[mt]  = *reinterpret_cast<const short8*>(&lA[rowOffA[mt] + slot0]);
      bfv[mt] = *reinterpret_cast<const short8*>(&lB[rowOffB[mt] + slot0]);
    }
#pragma unroll
    for (int mt = 0; mt < 4; ++mt)
#pragma unroll
      for (int nt = 0; nt < 4; ++nt)
        acc[mt][nt] = __builtin_amdgcn_mfma_f32_16x16x32_bf16(af[mt], bfv[nt], acc[mt][nt], 0, 0, 0);

#pragma unroll
    for (int mt = 0; mt < 4; ++mt) {
      af[mt]  = *reinterpret_cast<const short8*>(&lA[rowOffA[mt] + slot1]);
      bfv[mt] = *reinterpret_cast<const short8*>(&lB[rowOffB[mt] + slot1]);
    }
#pragma unroll
    for (int mt = 0; mt < 4; ++mt)
#pragma unroll
      for (int nt = 0; nt < 4; ++nt)
        acc[mt][nt] = __builtin_amdgcn_mfma_f32_16x16x32_bf16(af[mt], bfv[nt], acc[mt][nt], 0, 0, 0);

    __syncthreads();
  }

  // Fused epilogue. C layout: col = lane&15, row = lq*4 + reg — each lane's
  // 4 regs are one full img-set (4 rows) of one column. Set blocks are
  // 4-aligned in both dims, so cross-col sums are shfl_xor over lanes 1,2.
#pragma unroll
  for (int mt = 0; mt < 4; ++mt) {
#pragma unroll
    for (int nt = 0; nt < 4; ++nt) {
      f32x4 c = acc[mt][nt];
      float e0 = __expf(16.0f * c[0]);
      float e1 = __expf(16.0f * c[1]);
      float e2 = __expf(16.0f * c[2]);
      float e3 = __expf(16.0f * c[3]);
      float l = __logf(e0 + e1 + e2 + e3);          // left partial (per column)
      e0 += __shfl_xor(e0, 1); e0 += __shfl_xor(e0, 2);
      e1 += __shfl_xor(e1, 1); e1 += __shfl_xor(e1, 2);
      e2 += __shfl_xor(e2, 1); e2 += __shfl_xor(e2, 2);
      e3 += __shfl_xor(e3, 1); e3 += __shfl_xor(e3, 2);
      float r = __logf(e0) + __logf(e1) + __logf(e2) + __logf(e3);
      l += __shfl_xor(l, 1); l += __shfl_xor(l, 2);
      if ((lane & 3) == 0) {
        const int obi = ((bm0 + wm * 64 + mt * 16) >> 2) + lq;
        const int obt = ((bn0 + wn * 64 + nt * 16) >> 2) + (lm >> 2);
        out[(size_t)obi * BOUT + obt] = (r + l) * 0.0078125f;  // /128
      }
    }
  }
}

extern "C" void kernel_launch(void* const* d_in, const int* in_sizes, int n_in,
                              void* d_out, int out_size, void* d_ws, size_t ws_size,
                              hipStream_t stream) {
  const float* img = (const float*)d_in[0];
  const float* txt = (const float*)d_in[1];
  float* out = (float*)d_out;
  u16* bA = (u16*)d_ws;                       // 16 MiB
  u16* bB = bA + (size_t)N_ROWS * DIM;        // 16 MiB

  const int nPer = N_ROWS * DIM;              // 8388608 per input
  cast_kernel<<<dim3(nPer / (256 * 4)), dim3(256), 0, stream>>>(img, txt, bA, bB);

  dim3 ggrid(N_ROWS / BM, N_ROWS / BN);       // 64 x 64 = 4096 blocks
  gemm_chamfer<<<ggrid, dim3(256), 0, stream>>>(bA, bB, out);
}

// Round 4
// 289.592 us; speedup vs baseline: 1.0920x; 1.0920x over previous
//
#include <hip/hip_runtime.h>
#include <hip/hip_bf16.h>

// Problem constants (fixed by the reference):
//   img [8192,1024] f32, txt [8192,1024] f32, both l2-normalized
//   si=st=4, t=16, tts=1, DENOM=2  -> out[bi][bt] = (right+left)/128
//   out [2048,2048] f32
#define N_ROWS 8192
#define DIM    1024
#define BOUT   2048
#define BM 128
#define BN 128
#define BK 32

typedef unsigned short u16;
typedef __attribute__((ext_vector_type(4))) unsigned short u16x4;
typedef __attribute__((ext_vector_type(4))) float f32v4;    // clang ext-vector (nontemporal-ok)
typedef __attribute__((ext_vector_type(8))) short short8;   // 8 bf16 MFMA A/B frag
typedef __attribute__((ext_vector_type(4))) float f32x4;    // MFMA C/D frag

// fp32 -> bf16 round-to-nearest-even
__device__ __forceinline__ u16 f2bf(float f) {
  unsigned u = __float_as_uint(f);
  u += 0x7fffu + ((u >> 16) & 1u);
  return (u16)(u >> 16);
}

__global__ void cast_kernel(const float* __restrict__ a, const float* __restrict__ b,
                            u16* __restrict__ oa, u16* __restrict__ ob) {
  const size_t i = ((size_t)blockIdx.x * 256 + threadIdx.x) * 4;
  f32v4 va = __builtin_nontemporal_load(reinterpret_cast<const f32v4*>(a + i));
  f32v4 vb = __builtin_nontemporal_load(reinterpret_cast<const f32v4*>(b + i));
  u16x4 ua, ub;
  ua[0] = f2bf(va.x); ua[1] = f2bf(va.y); ua[2] = f2bf(va.z); ua[3] = f2bf(va.w);
  ub[0] = f2bf(vb.x); ub[1] = f2bf(vb.y); ub[2] = f2bf(vb.z); ub[3] = f2bf(vb.w);
  __builtin_nontemporal_store(ua, reinterpret_cast<u16x4*>(oa + i));
  __builtin_nontemporal_store(ub, reinterpret_cast<u16x4*>(ob + i));
}

// async 16B global->LDS copy (hardware dest = wave-uniform base + lane*16)
__device__ __forceinline__ void async_cp16(const u16* g, u16* l) {
  __builtin_amdgcn_global_load_lds(
      (const __attribute__((address_space(1))) void*)g,
      (__attribute__((address_space(3))) void*)l, 16, 0, 0);
}

// NT GEMM (dist = A.B^T) with fused smooth-chamfer 4x4-block epilogue.
// R0 structure (BK=32, 16 KiB LDS, VGPR ~76) + XOR bank swizzle:
// each 64 B LDS row holds 4 chunks of 16 B; chunk c stored at slot c^((r>>1)&3).
// Reader lanes (8 consecutive) then hit all 8 bank-quads exactly once -> 0 conflicts.
__global__ __launch_bounds__(256) void gemm_chamfer(
    const u16* __restrict__ A, const u16* __restrict__ B, float* __restrict__ out) {
  __shared__ __align__(16) u16 lA[BM * BK];   // 8 KiB
  __shared__ __align__(16) u16 lB[BN * BK];   // 8 KiB

  const int tid  = threadIdx.x;
  const int lane = tid & 63;
  const int wave = tid >> 6;
  const int wm = wave & 1;          // wave row (64 rows)
  const int wn = wave >> 1;         // wave col (64 cols)
  const int bm0 = blockIdx.x * BM;
  const int bn0 = blockIdx.y * BN;

  // staging: thread t -> row r = t>>2 (and r+64 in pass 2), LDS slot t&3.
  // global chunk fetched = (t&3) ^ ((r>>1)&3)   [(r+64)>>1 ≡ r>>1 mod 4 — same]
  // LDS dest = t*16 B (+4096 for pass 2) = wave-uniform + lane*16  ✓
  const int ldrow = tid >> 2;
  const int ldk   = (((tid & 3) ^ ((tid >> 3) & 3)) * 8);
  const u16* aSrc = A + (size_t)(bm0 + ldrow) * DIM + ldk;
  const u16* bSrc = B + (size_t)(bn0 + ldrow) * DIM + ldk;
  u16* aDst = &lA[ldrow * BK + (tid & 3) * 8];
  u16* bDst = &lB[ldrow * BK + (tid & 3) * 8];
  const size_t half = (size_t)64 * DIM;

  f32x4 acc[4][4] = {};

  const int lm = lane & 15;   // A/B row within 16-tile (= C col)
  const int lq = lane >> 4;   // k-quad for A/B frags; row-quad for C
  // reader: row R = wm*64 + mt*16 + lm -> (R>>1)&3 = (lm>>1)&3; want chunk lq
  const int slot = (lq ^ ((lm >> 1) & 3)) * 8;
  int rowOffA[4], rowOffB[4];
#pragma unroll
  for (int i = 0; i < 4; ++i) {
    rowOffA[i] = (wm * 64 + i * 16 + lm) * BK + slot;
    rowOffB[i] = (wn * 64 + i * 16 + lm) * BK + slot;
  }

  for (int k = 0; k < DIM; k += BK) {
    async_cp16(aSrc + k,        aDst);
    async_cp16(aSrc + k + half, aDst + 64 * BK);
    async_cp16(bSrc + k,        bDst);
    async_cp16(bSrc + k + half, bDst + 64 * BK);
    __syncthreads();

    short8 af[4], bfv[4];
#pragma unroll
    for (int mt = 0; mt < 4; ++mt) {
      af[mt]  = *reinterpret_cast<const short8*>(&lA[rowOffA[mt]]);
      bfv[mt] = *reinterpret_cast<const short8*>(&lB[rowOffB[mt]]);
    }
#pragma unroll
    for (int mt = 0; mt < 4; ++mt)
#pragma unroll
      for (int nt = 0; nt < 4; ++nt)
        acc[mt][nt] = __builtin_amdgcn_mfma_f32_16x16x32_bf16(af[mt], bfv[nt], acc[mt][nt], 0, 0, 0);

    __syncthreads();
  }

  // Fused epilogue. C layout: col = lane&15, row = lq*4 + reg — each lane's
  // 4 regs are one full img-set (4 rows) of one column. Set blocks are
  // 4-aligned in both dims, so cross-col sums are shfl_xor over lanes 1,2.
#pragma unroll
  for (int mt = 0; mt < 4; ++mt) {
#pragma unroll
    for (int nt = 0; nt < 4; ++nt) {
      f32x4 c = acc[mt][nt];
      float e0 = __expf(16.0f * c[0]);
      float e1 = __expf(16.0f * c[1]);
      float e2 = __expf(16.0f * c[2]);
      float e3 = __expf(16.0f * c[3]);
      float l = __logf(e0 + e1 + e2 + e3);          // left partial (per column)
      e0 += __shfl_xor(e0, 1); e0 += __shfl_xor(e0, 2);
      e1 += __shfl_xor(e1, 1); e1 += __shfl_xor(e1, 2);
      e2 += __shfl_xor(e2, 1); e2 += __shfl_xor(e2, 2);
      e3 += __shfl_xor(e3, 1); e3 += __shfl_xor(e3, 2);
      float r = __logf(e0) + __logf(e1) + __logf(e2) + __logf(e3);
      l += __shfl_xor(l, 1); l += __shfl_xor(l, 2);
      if ((lane & 3) == 0) {
        const int obi = ((bm0 + wm * 64 + mt * 16) >> 2) + lq;
        const int obt = ((bn0 + wn * 64 + nt * 16) >> 2) + (lm >> 2);
        out[(size_t)obi * BOUT + obt] = (r + l) * 0.0078125f;  // /128
      }
    }
  }
}

extern "C" void kernel_launch(void* const* d_in, const int* in_sizes, int n_in,
                              void* d_out, int out_size, void* d_ws, size_t ws_size,
                              hipStream_t stream) {
  const float* img = (const float*)d_in[0];
  const float* txt = (const float*)d_in[1];
  float* out = (float*)d_out;
  u16* bA = (u16*)d_ws;                       // 16 MiB
  u16* bB = bA + (size_t)N_ROWS * DIM;        // 16 MiB

  const int nPer = N_ROWS * DIM;              // 8388608 per input
  cast_kernel<<<dim3(nPer / (256 * 4)), dim3(256), 0, stream>>>(img, txt, bA, bB);

  dim3 ggrid(N_ROWS / BM, N_ROWS / BN);       // 64 x 64 = 4096 blocks
  gemm_chamfer<<<ggrid, dim3(256), 0, stream>>>(bA, bB, out);
}

// Round 5
// 288.329 us; speedup vs baseline: 1.0968x; 1.0044x over previous
//
#include <hip/hip_runtime.h>
#include <hip/hip_bf16.h>

// Problem constants (fixed by the reference):
//   img [8192,1024] f32, txt [8192,1024] f32, both l2-normalized
//   si=st=4, t=16, tts=1, DENOM=2  -> out[bi][bt] = (right+left)/128
//   out [2048,2048] f32
#define N_ROWS 8192
#define DIM    1024
#define BOUT   2048
#define BM 128
#define BN 128
#define BK 32

typedef unsigned short u16;
typedef __attribute__((ext_vector_type(4))) unsigned short u16x4;
typedef __attribute__((ext_vector_type(4))) float f32v4;     // clang ext-vector (nontemporal-ok)
typedef __attribute__((ext_vector_type(8))) short short8;    // 8 bf16 MFMA A/B frag (4 VGPRs)
typedef __attribute__((ext_vector_type(16))) float f32x16;   // 32x32 MFMA C/D frag

// fp32 -> bf16 round-to-nearest-even
__device__ __forceinline__ u16 f2bf(float f) {
  unsigned u = __float_as_uint(f);
  u += 0x7fffu + ((u >> 16) & 1u);
  return (u16)(u >> 16);
}

__global__ void cast_kernel(const float* __restrict__ a, const float* __restrict__ b,
                            u16* __restrict__ oa, u16* __restrict__ ob) {
  const size_t i = ((size_t)blockIdx.x * 256 + threadIdx.x) * 4;
  f32v4 va = __builtin_nontemporal_load(reinterpret_cast<const f32v4*>(a + i));
  f32v4 vb = __builtin_nontemporal_load(reinterpret_cast<const f32v4*>(b + i));
  u16x4 ua, ub;
  ua[0] = f2bf(va.x); ua[1] = f2bf(va.y); ua[2] = f2bf(va.z); ua[3] = f2bf(va.w);
  ub[0] = f2bf(vb.x); ub[1] = f2bf(vb.y); ub[2] = f2bf(vb.z); ub[3] = f2bf(vb.w);
  // cacheable stores: gemm rereads these from L2/L3
  *reinterpret_cast<u16x4*>(oa + i) = ua;
  *reinterpret_cast<u16x4*>(ob + i) = ub;
}

// async 16B global->LDS copy (hardware dest = wave-uniform base + lane*16)
__device__ __forceinline__ void async_cp16(const u16* g, u16* l) {
  __builtin_amdgcn_global_load_lds(
      (const __attribute__((address_space(1))) void*)g,
      (__attribute__((address_space(3))) void*)l, 16, 0, 0);
}

// NT GEMM (dist = A.B^T) with fused smooth-chamfer 4x4-block epilogue.
// 128x128 block tile, 4 waves (2x2), each wave 64x64 via 2x2 tiles of
// v_mfma_f32_32x32x16_bf16 (8 MFMA + 8 ds_read_b128 per BK=32 iter).
// LDS rows are 64 B = 4 chunks of 16 B; chunk c stored at slot c^((r>>1)&3)
// -> conflict-free for both the staging writes and the 32-row frag reads.
__global__ __launch_bounds__(256) void gemm_chamfer(
    const u16* __restrict__ A, const u16* __restrict__ B, float* __restrict__ out) {
  __shared__ __align__(16) u16 lA[BM * BK];   // 8 KiB
  __shared__ __align__(16) u16 lB[BN * BK];   // 8 KiB

  const int tid  = threadIdx.x;
  const int lane = tid & 63;
  const int wave = tid >> 6;
  const int wm = wave & 1;          // wave row (64 rows)
  const int wn = wave >> 1;         // wave col (64 cols)
  const int bm0 = blockIdx.x * BM;
  const int bn0 = blockIdx.y * BN;

  // staging: thread t -> row r = t>>2 (and r+64 in pass 2), LDS slot t&3.
  // global chunk fetched = (t&3) ^ ((r>>1)&3)   [(r+64)>>1 ≡ r>>1 mod 4]
  // LDS dest = t*16 B (+4096 for pass 2) = wave-uniform + lane*16  ✓
  const int ldrow = tid >> 2;
  const int ldk   = (((tid & 3) ^ ((tid >> 3) & 3)) * 8);
  const u16* aSrc = A + (size_t)(bm0 + ldrow) * DIM + ldk;
  const u16* bSrc = B + (size_t)(bn0 + ldrow) * DIM + ldk;
  u16* aDst = &lA[ldrow * BK + (tid & 3) * 8];
  u16* bDst = &lB[ldrow * BK + (tid & 3) * 8];
  const size_t half = (size_t)64 * DIM;

  f32x16 acc[2][2] = {};

  const int lm5 = lane & 31;   // A/B row within 32-tile (= C col)
  const int h   = lane >> 5;   // k-half selector for A/B frags; row offset for C
  // frag read for k-step ks: desired chunk c = 2*ks + h, slot = c ^ ((row>>1)&3)
  const int sw = (lm5 >> 1) & 3;
  const int slot0 = (( (h)     ) ^ sw) * 8;   // ks = 0
  const int slot1 = (( (h) | 2 ) ^ sw) * 8;   // ks = 1  (c = h + 2)
  int rowOffA[2], rowOffB[2];
#pragma unroll
  for (int i = 0; i < 2; ++i) {
    rowOffA[i] = (wm * 64 + i * 32 + lm5) * BK;
    rowOffB[i] = (wn * 64 + i * 32 + lm5) * BK;
  }

  for (int k = 0; k < DIM; k += BK) {
    async_cp16(aSrc + k,        aDst);
    async_cp16(aSrc + k + half, aDst + 64 * BK);
    async_cp16(bSrc + k,        bDst);
    async_cp16(bSrc + k + half, bDst + 64 * BK);
    __syncthreads();

    short8 af[2], bfv[2];
#pragma unroll
    for (int mt = 0; mt < 2; ++mt) {
      af[mt]  = *reinterpret_cast<const short8*>(&lA[rowOffA[mt] + slot0]);
      bfv[mt] = *reinterpret_cast<const short8*>(&lB[rowOffB[mt] + slot0]);
    }
#pragma unroll
    for (int mt = 0; mt < 2; ++mt)
#pragma unroll
      for (int nt = 0; nt < 2; ++nt)
        acc[mt][nt] = __builtin_amdgcn_mfma_f32_32x32x16_bf16(af[mt], bfv[nt], acc[mt][nt], 0, 0, 0);

#pragma unroll
    for (int mt = 0; mt < 2; ++mt) {
      af[mt]  = *reinterpret_cast<const short8*>(&lA[rowOffA[mt] + slot1]);
      bfv[mt] = *reinterpret_cast<const short8*>(&lB[rowOffB[mt] + slot1]);
    }
#pragma unroll
    for (int mt = 0; mt < 2; ++mt)
#pragma unroll
      for (int nt = 0; nt < 2; ++nt)
        acc[mt][nt] = __builtin_amdgcn_mfma_f32_32x32x16_bf16(af[mt], bfv[nt], acc[mt][nt], 0, 0, 0);

    __syncthreads();
  }

  // Fused epilogue. 32x32 C layout (m74/m101-verified):
  //   col = lane&31, row = (reg&3) + 8*(reg>>2) + 4*(lane>>5).
  // Each 4-reg group g holds rows [8g+4h .. 8g+4h+3] — a 4-aligned img-set —
  // of column lane&31. Cross-txt-set sums are shfl_xor over lanes 1,2.
#pragma unroll
  for (int mt = 0; mt < 2; ++mt) {
#pragma unroll
    for (int nt = 0; nt < 2; ++nt) {
#pragma unroll
      for (int g = 0; g < 4; ++g) {
        float e0 = __expf(16.0f * acc[mt][nt][4 * g + 0]);
        float e1 = __expf(16.0f * acc[mt][nt][4 * g + 1]);
        float e2 = __expf(16.0f * acc[mt][nt][4 * g + 2]);
        float e3 = __expf(16.0f * acc[mt][nt][4 * g + 3]);
        float l = __logf(e0 + e1 + e2 + e3);          // left partial (per column)
        e0 += __shfl_xor(e0, 1); e0 += __shfl_xor(e0, 2);
        e1 += __shfl_xor(e1, 1); e1 += __shfl_xor(e1, 2);
        e2 += __shfl_xor(e2, 1); e2 += __shfl_xor(e2, 2);
        e3 += __shfl_xor(e3, 1); e3 += __shfl_xor(e3, 2);
        float r = __logf(e0) + __logf(e1) + __logf(e2) + __logf(e3);
        l += __shfl_xor(l, 1); l += __shfl_xor(l, 2);
        if ((lane & 3) == 0) {
          const int obi = (bm0 + wm * 64 + mt * 32 + 8 * g + 4 * h) >> 2;
          const int obt = ((bn0 + wn * 64 + nt * 32) >> 2) + (lm5 >> 2);
          out[(size_t)obi * BOUT + obt] = (r + l) * 0.0078125f;  // /128
        }
      }
    }
  }
}

extern "C" void kernel_launch(void* const* d_in, const int* in_sizes, int n_in,
                              void* d_out, int out_size, void* d_ws, size_t ws_size,
                              hipStream_t stream) {
  const float* img = (const float*)d_in[0];
  const float* txt = (const float*)d_in[1];
  float* out = (float*)d_out;
  u16* bA = (u16*)d_ws;                       // 16 MiB
  u16* bB = bA + (size_t)N_ROWS * DIM;        // 16 MiB

  const int nPer = N_ROWS * DIM;              // 8388608 per input
  cast_kernel<<<dim3(nPer / (256 * 4)), dim3(256), 0, stream>>>(img, txt, bA, bB);

  dim3 ggrid(N_ROWS / BM, N_ROWS / BN);       // 64 x 64 = 4096 blocks
  gemm_chamfer<<<ggrid, dim3(256), 0, stream>>>(bA, bB, out);
}